// Round 18
// baseline (98.129 us; speedup 1.0000x reference)
//
#include <hip/hip_runtime.h>

// ZNCC 5x5, zero-padded, count_include_pad means.
// x,y: (4,3,512,512) f32 -> out: (4,1,512,512) f32
// Round 18: amortization geometry. 32x32 tiles, 128-thread blocks (16x8),
// 2col x 4row strips (8 px/thread) -> 1024 blocks = 8 blocks/CU = 16
// waves/CU (4 w/SIMD) AND 3 ds_read_b128/px (was 4.5) AND colsums/means
// amortized over 4 output rows. 6-slot rotating register window: rows 0-5
// batched, o=0,1 computed, rows 6,7 reload retired slots 0,1 for o=2,3.
// Single LDS buffer (10.4KB x8 = 83KB/CU); barriers sync only 2 waves and
// 8 independent blocks/CU cover each other's stalls.

constexpr int W  = 512, H = 512, C = 3, NB = 4;
constexpr int PLANE = H * W;
constexpr int TW = 32, TH = 32, HALO = 2;
constexpr int LW = TW + 2 * HALO;   // 36 pairs (image cols) per row
constexpr int LH = TH + 2 * HALO;   // 36 rows
constexpr int LSZ  = LW * LH;       // 1296 pairs
constexpr int NCH  = LSZ / 2;       // 648 float2-chunks (LW even -> 18/row)
constexpr int NPF  = 6;             // chunks per thread (128 thr): 768 >= 648

typedef float f2 __attribute__((ext_vector_type(2)));

__device__ __forceinline__ void prefetch_plane(const float* __restrict__ xb,
                                               const float* __restrict__ yb,
                                               const int* goff, const float* fm,
                                               float2* px, float2* py) {
    #pragma unroll
    for (int k = 0; k < NPF; ++k) {
        const float2 a = *reinterpret_cast<const float2*>(xb + goff[k]);
        const float2 b = *reinterpret_cast<const float2*>(yb + goff[k]);
        px[k] = make_float2(a.x * fm[k], a.y * fm[k]);
        py[k] = make_float2(b.x * fm[k], b.y * fm[k]);
    }
}

__device__ __forceinline__ void write_tile(f2* __restrict__ dst,
                                           const float2* px, const float2* py,
                                           int tid) {
    #pragma unroll
    for (int k = 0; k < NPF; ++k) {
        const int j = tid + 128 * k;                  // chunk id
        if (j < NCH) {
            const float4 v = make_float4(px[k].x, py[k].x, px[k].y, py[k].y);
            *reinterpret_cast<float4*>(&dst[2 * j]) = v;  // ds_write_b128
        }
    }
}

__device__ __forceinline__ void load_row(f2* wr, const f2* __restrict__ tile,
                                         int base) {
    const float4 u0 = *reinterpret_cast<const float4*>(&tile[base]);
    const float4 u1 = *reinterpret_cast<const float4*>(&tile[base + 2]);
    const float4 u2 = *reinterpret_cast<const float4*>(&tile[base + 4]);
    wr[0] = f2{u0.x, u0.y}; wr[1] = f2{u0.z, u0.w};
    wr[2] = f2{u1.x, u1.y}; wr[3] = f2{u1.z, u1.w};
    wr[4] = f2{u2.x, u2.y}; wr[5] = f2{u2.z, u2.w};
}

// 6-slot rotating window over a staged 36x36 tile; 4 output rows x 2 cols.
__device__ __forceinline__ void compute_channel(const f2* __restrict__ tile,
                                                int ry, int cx,
                                                float* ch0, float* ch1) {
    const float EPS = 1e-4f;

    f2 w[6][6];
    #pragma unroll
    for (int k = 0; k < 6; ++k)
        load_row(w[k], tile, (4 * ry + k) * LW + cx);

    f2 cs[6];
    #pragma unroll
    for (int j = 0; j < 6; ++j)
        cs[j] = (w[0][j] + w[1][j]) + (w[2][j] + w[3][j]);

    #pragma unroll
    for (int o = 0; o < 4; ++o) {
        const int sN = (o + 4) % 6;          // slot of incoming window row o+4
        if (o >= 2)                          // rows 6,7 reload retired slots 0,1
            load_row(w[sN], tile, (4 * ry + o + 4) * LW + cx);

        #pragma unroll
        for (int j = 0; j < 6; ++j) cs[j] += w[sN][j];

        const f2 m4 = (cs[1] + cs[2]) + (cs[3] + cs[4]);
        const f2 M0 = (m4 + cs[0]) * (1.f / 25.f);
        const f2 M1 = (m4 + cs[5]) * (1.f / 25.f);
        const float mx0 = M0.x, my0 = M0.y;
        const float mx1 = M1.x, my1 = M1.y;

        float a0 = 0.f, a1 = 0.f;
        #pragma unroll
        for (int k = 0; k < 5; ++k) {
            const int s = (o + k) % 6;       // static after unroll
            #pragma unroll
            for (int j = 0; j < 5; ++j) {
                {
                    const float dx  = w[s][j].x - mx0;
                    const float dy  = w[s][j].y - my0;
                    const float num = fabsf(dx * dy) + EPS;
                    const float qx  = __builtin_fmaf(dx, dx, EPS);
                    const float qy  = __builtin_fmaf(dy, dy, EPS);
                    a0 = __builtin_fmaf(num, __builtin_amdgcn_rsqf(qx * qy), a0);
                }
                {
                    const float dx  = w[s][j + 1].x - mx1;
                    const float dy  = w[s][j + 1].y - my1;
                    const float num = fabsf(dx * dy) + EPS;
                    const float qx  = __builtin_fmaf(dx, dx, EPS);
                    const float qy  = __builtin_fmaf(dy, dy, EPS);
                    a1 = __builtin_fmaf(num, __builtin_amdgcn_rsqf(qx * qy), a1);
                }
            }
        }
        ch0[o] += fminf(fmaxf(a0 * (1.f / 25.f), 0.f), 1.f);
        ch1[o] += fminf(fmaxf(a1 * (1.f / 25.f), 0.f), 1.f);

        #pragma unroll
        for (int j = 0; j < 6; ++j) cs[j] -= w[o % 6][j];   // retire row o
    }
}

__global__ __launch_bounds__(128, 4)
void zncc_kernel(const float* __restrict__ x,
                 const float* __restrict__ y,
                 float* __restrict__ out) {
    __shared__ f2 sb[LSZ];              // single interleaved tile, 10368 B

    const int tid = threadIdx.x;
    const int tc  = tid & 15;           // 16 col-pairs -> 32 cols
    const int ry  = tid >> 4;           // 0..7 -> rows 4*ry..4*ry+3
    const int cx  = 2 * tc;             // pair-col base of window
    const int w0  = blockIdx.x * TW;
    const int h0  = blockIdx.y * TH;
    const int b   = blockIdx.z;

    // staging address math, once. chunk j: row l=j/18, col m=2*(j%18);
    // gc = w0+m-2 even (w0 mult of 32) -> a chunk never straddles the edge.
    int   goff[NPF];
    float fm[NPF];
    #pragma unroll
    for (int k = 0; k < NPF; ++k) {
        const int j  = tid + 128 * k;
        const int l  = j / 18;
        const int m  = 2 * (j - l * 18);
        const int gr = h0 + l - HALO;
        const int gc = w0 + m - HALO;
        const bool ok = (j < NCH) && ((unsigned)gr < (unsigned)H) &&
                        ((unsigned)gc < (unsigned)W);
        goff[k] = ok ? gr * W + gc : 0;
        fm[k]   = ok ? 1.f : 0.f;
    }

    const float* xb0 = x + (size_t)(b * C) * PLANE;
    const float* yb0 = y + (size_t)(b * C) * PLANE;

    float ch0[4] = {0.f, 0.f, 0.f, 0.f};
    float ch1[4] = {0.f, 0.f, 0.f, 0.f};
    float2 px[NPF], py[NPF];

    // stage channel 0
    prefetch_plane(xb0, yb0, goff, fm, px, py);
    write_tile(&sb[0], px, py, tid);
    __syncthreads();

    // channel 0: prefetch ch1, compute, then overwrite buffer
    prefetch_plane(xb0 + PLANE, yb0 + PLANE, goff, fm, px, py);
    compute_channel(&sb[0], ry, cx, ch0, ch1);
    __syncthreads();                    // all waves done reading
    write_tile(&sb[0], px, py, tid);
    __syncthreads();

    // channel 1: prefetch ch2, compute, overwrite
    prefetch_plane(xb0 + 2 * PLANE, yb0 + 2 * PLANE, goff, fm, px, py);
    compute_channel(&sb[0], ry, cx, ch0, ch1);
    __syncthreads();
    write_tile(&sb[0], px, py, tid);
    __syncthreads();

    // channel 2
    compute_channel(&sb[0], ry, cx, ch0, ch1);

    // write 2x4 output strip
    #pragma unroll
    for (int o = 0; o < 4; ++o) {
        float2 v;
        v.x = ch0[o] * (1.f / 3.f);
        v.y = ch1[o] * (1.f / 3.f);
        *reinterpret_cast<float2*>(
            &out[((size_t)b * H + h0 + 4 * ry + o) * W + w0 + cx]) = v;
    }
}

extern "C" void kernel_launch(void* const* d_in, const int* in_sizes, int n_in,
                              void* d_out, int out_size, void* d_ws, size_t ws_size,
                              hipStream_t stream) {
    const float* x = (const float*)d_in[0];
    const float* y = (const float*)d_in[1];
    float* out = (float*)d_out;
    dim3 grid(W / TW, H / TH, NB);   // 16, 16, 4 = 1024 blocks (8 per CU)
    zncc_kernel<<<grid, dim3(128), 0, stream>>>(x, y, out);
}

// Round 19
// 34.002 us; speedup vs baseline: 2.8860x; 2.8860x over previous
//
#include <hip/hip_runtime.h>

// ZNCC 5x5, zero-padded, count_include_pad means.
// x,y: (4,3,512,512) f32 -> out: (4,1,512,512) f32
// Round 19: R15/R17 champion (27.79us) + final micro-bundle:
//  (a) split accumulators (even/odd k) -> halves the 25-deep acc fma chain;
//  (b) clip removed (AM-GM: |ab|+c <= sqrt((a^2+c)(b^2+c)), so ncc in (0,1]
//      exactly; fp deviation ~1e-7 << 2e-2 threshold) and the /25, /3
//      scalings folded into one x(1/75) at the end. ~40 insts/thread saved.
// Model after R10/R13/R15/R16/R17: kernel is VALU datapath-lane-cycle bound;
// term math (8 ops + rsq) is algebraically minimal in f32.

constexpr int W  = 512, H = 512, C = 3, NB = 4;
constexpr int PLANE = H * W;
constexpr int TW = 64, TH = 16, HALO = 2;
constexpr int LW = TW + 2 * HALO;   // 68 pairs per row
constexpr int LH = TH + 2 * HALO;   // 20
constexpr int LSZ  = LW * LH;       // 1360 pairs
constexpr int NCH  = LSZ / 2;       // 680 float2-chunks
constexpr int LPAD = 1536;          // 768 chunks * 2 (pad absorbs tail)
constexpr int NPF  = 3;             // chunks per thread per array

typedef float f2 __attribute__((ext_vector_type(2)));

__device__ __forceinline__ void prefetch_plane(const float* __restrict__ xb,
                                               const float* __restrict__ yb,
                                               const int* goff, const float* fm,
                                               float2* px, float2* py) {
    #pragma unroll
    for (int k = 0; k < NPF; ++k) {
        const float2 a = *reinterpret_cast<const float2*>(xb + goff[k]);
        const float2 b = *reinterpret_cast<const float2*>(yb + goff[k]);
        px[k] = make_float2(a.x * fm[k], a.y * fm[k]);
        py[k] = make_float2(b.x * fm[k], b.y * fm[k]);
    }
}

__device__ __forceinline__ void write_tile(f2* __restrict__ dst,
                                           const float2* px, const float2* py,
                                           int tid) {
    #pragma unroll
    for (int k = 0; k < NPF; ++k) {
        const int j = tid + 256 * k;                  // chunk id
        const float4 v = make_float4(px[k].x, py[k].x, px[k].y, py[k].y);
        *reinterpret_cast<float4*>(&dst[2 * j]) = v;  // ds_write_b128
    }
}

// 6-row x 6-pair window batched into regs; packed colsums, scalar terms,
// split accumulators, raw (unscaled, unclipped) channel sums.
__device__ __forceinline__ void compute_channel(const f2* __restrict__ tile,
                                                int ry, int cx,
                                                float* ch0, float* ch1) {
    const float EPS = 1e-4f;

    // ---- one burst: 18 independent ds_read_b128 ----
    f2 w[6][6];
    #pragma unroll
    for (int k = 0; k < 6; ++k) {
        const int base = (2 * ry + k) * LW + cx;
        const float4 u0 = *reinterpret_cast<const float4*>(&tile[base]);
        const float4 u1 = *reinterpret_cast<const float4*>(&tile[base + 2]);
        const float4 u2 = *reinterpret_cast<const float4*>(&tile[base + 4]);
        w[k][0] = f2{u0.x, u0.y}; w[k][1] = f2{u0.z, u0.w};
        w[k][2] = f2{u1.x, u1.y}; w[k][3] = f2{u1.z, u1.w};
        w[k][4] = f2{u2.x, u2.y}; w[k][5] = f2{u2.z, u2.w};
    }

    // ---- init column sums from rows 0..3 (packed) ----
    f2 cs[6];
    #pragma unroll
    for (int j = 0; j < 6; ++j)
        cs[j] = (w[0][j] + w[1][j]) + (w[2][j] + w[3][j]);

    #pragma unroll
    for (int o = 0; o < 2; ++o) {
        #pragma unroll
        for (int j = 0; j < 6; ++j) cs[j] += w[o + 4][j];

        const f2 m4 = (cs[1] + cs[2]) + (cs[3] + cs[4]);
        const f2 M0 = (m4 + cs[0]) * (1.f / 25.f);
        const f2 M1 = (m4 + cs[5]) * (1.f / 25.f);
        const float mx0 = M0.x, my0 = M0.y;
        const float mx1 = M1.x, my1 = M1.y;

        // split accumulators: even k / odd k
        float a0e = 0.f, a0o = 0.f, a1e = 0.f, a1o = 0.f;
        #pragma unroll
        for (int k = 0; k < 5; ++k) {
            #pragma unroll
            for (int j = 0; j < 5; ++j) {
                {
                    const float dx  = w[o + k][j].x - mx0;
                    const float dy  = w[o + k][j].y - my0;
                    const float num = fabsf(dx * dy) + EPS;
                    const float qx  = __builtin_fmaf(dx, dx, EPS);
                    const float qy  = __builtin_fmaf(dy, dy, EPS);
                    const float r   = __builtin_amdgcn_rsqf(qx * qy);
                    if (k & 1) a0o = __builtin_fmaf(num, r, a0o);
                    else       a0e = __builtin_fmaf(num, r, a0e);
                }
                {
                    const float dx  = w[o + k][j + 1].x - mx1;
                    const float dy  = w[o + k][j + 1].y - my1;
                    const float num = fabsf(dx * dy) + EPS;
                    const float qx  = __builtin_fmaf(dx, dx, EPS);
                    const float qy  = __builtin_fmaf(dy, dy, EPS);
                    const float r   = __builtin_amdgcn_rsqf(qx * qy);
                    if (k & 1) a1o = __builtin_fmaf(num, r, a1o);
                    else       a1e = __builtin_fmaf(num, r, a1e);
                }
            }
        }
        ch0[o] += a0e + a0o;     // raw sum in (0, 25]; no clip needed (AM-GM)
        ch1[o] += a1e + a1o;

        #pragma unroll
        for (int j = 0; j < 6; ++j) cs[j] -= w[o][j];
    }
}

__global__ __launch_bounds__(256, 4)
void zncc_kernel(const float* __restrict__ x,
                 const float* __restrict__ y,
                 float* __restrict__ out) {
    __shared__ f2 sb[2][LPAD];          // interleaved (x,y) tiles, 24576 B

    const int tid = threadIdx.x;
    const int tx  = tid & 31;           // 32 col-pairs -> 64 cols
    const int ry  = tid >> 5;           // 0..7 -> rows 2*ry, 2*ry+1
    const int cx  = 2 * tx;
    const int w0  = blockIdx.x * TW;
    const int h0  = blockIdx.y * TH;
    const int b   = blockIdx.z;

    // staging address math, once (reused for all 3 channels), chunk-based
    int   goff[NPF];
    float fm[NPF];
    #pragma unroll
    for (int k = 0; k < NPF; ++k) {
        const int j  = tid + 256 * k;
        const int l  = j / 34;
        const int m  = 2 * (j - l * 34);
        const int gr = h0 + l - HALO;
        const int gc = w0 + m - HALO;
        const bool ok = (j < NCH) && ((unsigned)gr < (unsigned)H) &&
                        ((unsigned)gc < (unsigned)W);
        goff[k] = ok ? gr * W + gc : 0;
        fm[k]   = ok ? 1.f : 0.f;
    }

    const float* xb0 = x + (size_t)(b * C) * PLANE;
    const float* yb0 = y + (size_t)(b * C) * PLANE;

    float ch0[2] = {0.f, 0.f};
    float ch1[2] = {0.f, 0.f};
    float2 px[NPF], py[NPF];

    // stage channel 0 -> buf0
    prefetch_plane(xb0, yb0, goff, fm, px, py);
    write_tile(&sb[0][0], px, py, tid);
    __syncthreads();

    // channel 0: prefetch ch1, compute from buf0, write buf1
    prefetch_plane(xb0 + PLANE, yb0 + PLANE, goff, fm, px, py);
    compute_channel(&sb[0][0], ry, cx, ch0, ch1);
    write_tile(&sb[1][0], px, py, tid);
    __syncthreads();

    // channel 1: prefetch ch2, compute from buf1, write buf0
    prefetch_plane(xb0 + 2 * PLANE, yb0 + 2 * PLANE, goff, fm, px, py);
    compute_channel(&sb[1][0], ry, cx, ch0, ch1);
    write_tile(&sb[0][0], px, py, tid);
    __syncthreads();

    // channel 2: compute from buf0
    compute_channel(&sb[0][0], ry, cx, ch0, ch1);

    // write 2x2 output strip; single fold of /25 and /3
    #pragma unroll
    for (int o = 0; o < 2; ++o) {
        float2 v;
        v.x = ch0[o] * (1.f / 75.f);
        v.y = ch1[o] * (1.f / 75.f);
        *reinterpret_cast<float2*>(
            &out[((size_t)b * H + h0 + 2 * ry + o) * W + w0 + cx]) = v;
    }
}

extern "C" void kernel_launch(void* const* d_in, const int* in_sizes, int n_in,
                              void* d_out, int out_size, void* d_ws, size_t ws_size,
                              hipStream_t stream) {
    const float* x = (const float*)d_in[0];
    const float* y = (const float*)d_in[1];
    float* out = (float*)d_out;
    dim3 grid(W / TW, H / TH, NB);   // 8, 32, 4 = 1024 blocks (4 per CU)
    zncc_kernel<<<grid, dim3(256), 0, stream>>>(x, y, out);
}

// Round 20
// 28.014 us; speedup vs baseline: 3.5029x; 1.2138x over previous
//
#include <hip/hip_runtime.h>

// ZNCC 5x5, zero-padded, count_include_pad means.
// x,y: (4,3,512,512) f32 -> out: (4,1,512,512) f32
// Round 20: REVERT to the R15/R17 champion (27.79us, reproduced twice).
// R19's split-accumulator bundle regressed (+6us): it attacked dependency
// latency (proven non-binding by R10/R15) while adding instruction mass /
// register pressure (proven binding by R13). Final ledger: VALU-datapath-
// cycle bound; TLP null x2; I$ null; banks 0; LDS ~18%; HBM ~10%; term math
// algebraically minimal in f32; staging pipelined+vectorized; addressing
// hoisted. This structure is at its practical plateau.

constexpr int W  = 512, H = 512, C = 3, NB = 4;
constexpr int PLANE = H * W;
constexpr int TW = 64, TH = 16, HALO = 2;
constexpr int LW = TW + 2 * HALO;   // 68 pairs per row
constexpr int LH = TH + 2 * HALO;   // 20
constexpr int LSZ  = LW * LH;       // 1360 pairs
constexpr int NCH  = LSZ / 2;       // 680 float2-chunks
constexpr int LPAD = 1536;          // 768 chunks * 2 (pad absorbs tail)
constexpr int NPF  = 3;             // chunks per thread per array

typedef float f2 __attribute__((ext_vector_type(2)));

__device__ __forceinline__ void prefetch_plane(const float* __restrict__ xb,
                                               const float* __restrict__ yb,
                                               const int* goff, const float* fm,
                                               float2* px, float2* py) {
    #pragma unroll
    for (int k = 0; k < NPF; ++k) {
        const float2 a = *reinterpret_cast<const float2*>(xb + goff[k]);
        const float2 b = *reinterpret_cast<const float2*>(yb + goff[k]);
        px[k] = make_float2(a.x * fm[k], a.y * fm[k]);
        py[k] = make_float2(b.x * fm[k], b.y * fm[k]);
    }
}

__device__ __forceinline__ void write_tile(f2* __restrict__ dst,
                                           const float2* px, const float2* py,
                                           int tid) {
    #pragma unroll
    for (int k = 0; k < NPF; ++k) {
        const int j = tid + 256 * k;                  // chunk id
        const float4 v = make_float4(px[k].x, py[k].x, px[k].y, py[k].y);
        *reinterpret_cast<float4*>(&dst[2 * j]) = v;  // ds_write_b128
    }
}

// 6-row x 6-pair window batched into regs; packed colsums, scalar terms.
__device__ __forceinline__ void compute_channel(const f2* __restrict__ tile,
                                                int ry, int cx,
                                                float* ch0, float* ch1) {
    const float EPS = 1e-4f;

    // ---- one burst: 18 independent ds_read_b128 ----
    f2 w[6][6];
    #pragma unroll
    for (int k = 0; k < 6; ++k) {
        const int base = (2 * ry + k) * LW + cx;
        const float4 u0 = *reinterpret_cast<const float4*>(&tile[base]);
        const float4 u1 = *reinterpret_cast<const float4*>(&tile[base + 2]);
        const float4 u2 = *reinterpret_cast<const float4*>(&tile[base + 4]);
        w[k][0] = f2{u0.x, u0.y}; w[k][1] = f2{u0.z, u0.w};
        w[k][2] = f2{u1.x, u1.y}; w[k][3] = f2{u1.z, u1.w};
        w[k][4] = f2{u2.x, u2.y}; w[k][5] = f2{u2.z, u2.w};
    }

    // ---- init column sums from rows 0..3 (packed, aligned operands) ----
    f2 cs[6];
    #pragma unroll
    for (int j = 0; j < 6; ++j)
        cs[j] = (w[0][j] + w[1][j]) + (w[2][j] + w[3][j]);

    #pragma unroll
    for (int o = 0; o < 2; ++o) {
        #pragma unroll
        for (int j = 0; j < 6; ++j) cs[j] += w[o + 4][j];

        // means for px0 (cols 0..4) and px1 (cols 1..5), packed
        const f2 m4 = (cs[1] + cs[2]) + (cs[3] + cs[4]);
        const f2 M0 = (m4 + cs[0]) * (1.f / 25.f);   // (mx0, my0)
        const f2 M1 = (m4 + cs[5]) * (1.f / 25.f);   // (mx1, my1)
        const float mx0 = M0.x, my0 = M0.y;
        const float mx1 = M1.x, my1 = M1.y;

        float a0 = 0.f, a1 = 0.f;
        #pragma unroll
        for (int k = 0; k < 5; ++k) {
            #pragma unroll
            for (int j = 0; j < 5; ++j) {
                {
                    const float dx  = w[o + k][j].x - mx0;
                    const float dy  = w[o + k][j].y - my0;
                    const float num = fabsf(dx * dy) + EPS;
                    const float qx  = __builtin_fmaf(dx, dx, EPS);
                    const float qy  = __builtin_fmaf(dy, dy, EPS);
                    a0 = __builtin_fmaf(num, __builtin_amdgcn_rsqf(qx * qy), a0);
                }
                {
                    const float dx  = w[o + k][j + 1].x - mx1;
                    const float dy  = w[o + k][j + 1].y - my1;
                    const float num = fabsf(dx * dy) + EPS;
                    const float qx  = __builtin_fmaf(dx, dx, EPS);
                    const float qy  = __builtin_fmaf(dy, dy, EPS);
                    a1 = __builtin_fmaf(num, __builtin_amdgcn_rsqf(qx * qy), a1);
                }
            }
        }
        ch0[o] += fminf(fmaxf(a0 * (1.f / 25.f), 0.f), 1.f);
        ch1[o] += fminf(fmaxf(a1 * (1.f / 25.f), 0.f), 1.f);

        #pragma unroll
        for (int j = 0; j < 6; ++j) cs[j] -= w[o][j];
    }
}

__global__ __launch_bounds__(256, 4)
void zncc_kernel(const float* __restrict__ x,
                 const float* __restrict__ y,
                 float* __restrict__ out) {
    __shared__ f2 sb[2][LPAD];          // interleaved (x,y) tiles, 24576 B

    const int tid = threadIdx.x;
    const int tx  = tid & 31;           // 32 col-pairs -> 64 cols
    const int ry  = tid >> 5;           // 0..7 -> rows 2*ry, 2*ry+1
    const int cx  = 2 * tx;
    const int w0  = blockIdx.x * TW;
    const int h0  = blockIdx.y * TH;
    const int b   = blockIdx.z;

    // staging address math, once (reused for all 3 channels), chunk-based
    int   goff[NPF];
    float fm[NPF];
    #pragma unroll
    for (int k = 0; k < NPF; ++k) {
        const int j  = tid + 256 * k;
        const int l  = j / 34;
        const int m  = 2 * (j - l * 34);
        const int gr = h0 + l - HALO;
        const int gc = w0 + m - HALO;
        const bool ok = (j < NCH) && ((unsigned)gr < (unsigned)H) &&
                        ((unsigned)gc < (unsigned)W);
        goff[k] = ok ? gr * W + gc : 0;
        fm[k]   = ok ? 1.f : 0.f;
    }

    const float* xb0 = x + (size_t)(b * C) * PLANE;
    const float* yb0 = y + (size_t)(b * C) * PLANE;

    float ch0[2] = {0.f, 0.f};
    float ch1[2] = {0.f, 0.f};
    float2 px[NPF], py[NPF];

    // stage channel 0 -> buf0
    prefetch_plane(xb0, yb0, goff, fm, px, py);
    write_tile(&sb[0][0], px, py, tid);
    __syncthreads();

    // channel 0: prefetch ch1, compute from buf0, write buf1
    prefetch_plane(xb0 + PLANE, yb0 + PLANE, goff, fm, px, py);
    compute_channel(&sb[0][0], ry, cx, ch0, ch1);
    write_tile(&sb[1][0], px, py, tid);
    __syncthreads();

    // channel 1: prefetch ch2, compute from buf1, write buf0
    prefetch_plane(xb0 + 2 * PLANE, yb0 + 2 * PLANE, goff, fm, px, py);
    compute_channel(&sb[1][0], ry, cx, ch0, ch1);
    write_tile(&sb[0][0], px, py, tid);
    __syncthreads();

    // channel 2: compute from buf0
    compute_channel(&sb[0][0], ry, cx, ch0, ch1);

    // write 2x2 output strip
    #pragma unroll
    for (int o = 0; o < 2; ++o) {
        float2 v;
        v.x = ch0[o] * (1.f / 3.f);
        v.y = ch1[o] * (1.f / 3.f);
        *reinterpret_cast<float2*>(
            &out[((size_t)b * H + h0 + 2 * ry + o) * W + w0 + cx]) = v;
    }
}

extern "C" void kernel_launch(void* const* d_in, const int* in_sizes, int n_in,
                              void* d_out, int out_size, void* d_ws, size_t ws_size,
                              hipStream_t stream) {
    const float* x = (const float*)d_in[0];
    const float* y = (const float*)d_in[1];
    float* out = (float*)d_out;
    dim3 grid(W / TW, H / TH, NB);   // 8, 32, 4 = 1024 blocks (4 per CU)
    zncc_kernel<<<grid, dim3(256), 0, stream>>>(x, y, out);
}